// Round 1
// baseline (1317.501 us; speedup 1.0000x reference)
//
#include <hip/hip_runtime.h>
#include <math.h>

// Wave-uniform broadcast of lane k's value (VALU v_readlane, avoids LDS pipe)
__device__ __forceinline__ float bcast(float v, int k) {
  return __int_as_float(__builtin_amdgcn_readlane(__float_as_int(v), k));
}

// ---------------- CSR build: histogram ----------------
__global__ __launch_bounds__(256) void hist_k(const int* __restrict__ dst, int* __restrict__ deg, int E) {
  for (int e = blockIdx.x * blockDim.x + threadIdx.x; e < E; e += gridDim.x * blockDim.x)
    atomicAdd(&deg[dst[e]], 1);
}

// ---------------- CSR build: 3-kernel exclusive scan ----------------
__global__ __launch_bounds__(1024) void scan1_k(const int* __restrict__ deg, int* __restrict__ rp,
                                                int* __restrict__ bsum, int n) {
  __shared__ int buf[2][1024];
  int tid = threadIdx.x;
  int i = blockIdx.x * 1024 + tid;
  int v = (i < n) ? deg[i] : 0;
  int pp = 0;
  buf[0][tid] = v;
  __syncthreads();
  for (int off = 1; off < 1024; off <<= 1) {
    int t = buf[pp][tid];
    if (tid >= off) t += buf[pp][tid - off];
    buf[pp ^ 1][tid] = t;
    pp ^= 1;
    __syncthreads();
  }
  int inc = buf[pp][tid];
  if (i < n) rp[i] = inc - v;               // exclusive within block
  if (tid == 1023) bsum[blockIdx.x] = inc;  // block total
}

__global__ __launch_bounds__(256) void scan2_k(int* __restrict__ bsum, int nb) {
  __shared__ int buf[2][256];
  int tid = threadIdx.x;
  int v = (tid < nb) ? bsum[tid] : 0;
  int pp = 0;
  buf[0][tid] = v;
  __syncthreads();
  for (int off = 1; off < 256; off <<= 1) {
    int t = buf[pp][tid];
    if (tid >= off) t += buf[pp][tid - off];
    buf[pp ^ 1][tid] = t;
    pp ^= 1;
    __syncthreads();
  }
  if (tid < nb) bsum[tid] = buf[pp][tid] - v;  // exclusive block offsets
}

__global__ __launch_bounds__(1024) void scan3_k(int* __restrict__ rp, int* __restrict__ cur,
                                                const int* __restrict__ bsum, int n, int E) {
  int i = blockIdx.x * 1024 + threadIdx.x;
  if (i < n) {
    int v = rp[i] + bsum[blockIdx.x];
    rp[i] = v;
    cur[i] = v;
  }
  if (i == 0) rp[n] = E;
}

// ---------------- CSR build: counting-sort scatter ----------------
__global__ __launch_bounds__(256) void scatter_k(const int* __restrict__ src, const int* __restrict__ dst,
                                                 const float* __restrict__ w, int* __restrict__ cur,
                                                 int* __restrict__ ssrc, float* __restrict__ sw, int E) {
  for (int e = blockIdx.x * blockDim.x + threadIdx.x; e < E; e += gridDim.x * blockDim.x) {
    int d = dst[e];
    int pos = atomicAdd(&cur[d], 1);
    ssrc[pos] = src[e];
    sw[pos] = w[e];
  }
}

// ---------------- h = relu(x @ W_in + b_in) ----------------
// One wave per node; lane = output feature. W_in column `lane` held in 128 VGPRs.
__global__ __launch_bounds__(256) void ingemm_k(const float* __restrict__ x, const float* __restrict__ Win,
                                                const float* __restrict__ bin, float* __restrict__ x0, int n) {
  int lane = threadIdx.x & 63;
  int wave = threadIdx.x >> 6;
  float Wreg[128];
#pragma unroll
  for (int k = 0; k < 128; ++k) Wreg[k] = Win[k * 64 + lane];
  float bb = bin[lane];
  for (int node = blockIdx.x * 4 + wave; node < n; node += gridDim.x * 4) {
    float xa = x[(size_t)node * 128 + lane];
    float xb = x[(size_t)node * 128 + 64 + lane];
    float a0 = 0.f, a1 = 0.f;
#pragma unroll
    for (int k = 0; k < 64; k += 2) {
      a0 = fmaf(bcast(xa, k), Wreg[k], a0);
      a1 = fmaf(bcast(xa, k + 1), Wreg[k + 1], a1);
    }
#pragma unroll
    for (int k = 0; k < 64; k += 2) {
      a0 = fmaf(bcast(xb, k), Wreg[64 + k], a0);
      a1 = fmaf(bcast(xb, k + 1), Wreg[64 + k + 1], a1);
    }
    float r = a0 + a1 + bb;
    x0[(size_t)node * 64 + lane] = fmaxf(r, 0.f);
  }
}

// ---------------- one GCNII layer ----------------
// agg = CSR-SpMM(h_in); hh = 0.9*agg + 0.1*x0; h_out = relu((1-beta)*hh + beta*(hh@W))
__global__ __launch_bounds__(256) void layer_k(const float* __restrict__ hin, const float* __restrict__ x0,
                                               const int* __restrict__ rp, const int* __restrict__ ss,
                                               const float* __restrict__ swt, const float* __restrict__ W,
                                               float* __restrict__ hout, float beta, int n) {
  int lane = threadIdx.x & 63;
  int wave = threadIdx.x >> 6;
  float Wreg[64];
#pragma unroll
  for (int k = 0; k < 64; ++k) Wreg[k] = W[k * 64 + lane];
  for (int node = blockIdx.x * 4 + wave; node < n; node += gridDim.x * 4) {
    int beg = rp[node], end = rp[node + 1];
    float acc = 0.f;
    int e = beg;
    for (; e + 1 < end; e += 2) {
      int s0 = ss[e], s1 = ss[e + 1];
      float w0 = swt[e], w1 = swt[e + 1];
      float a0 = hin[(size_t)s0 * 64 + lane];
      float a1 = hin[(size_t)s1 * 64 + lane];
      acc = fmaf(a0, w0, acc);
      acc = fmaf(a1, w1, acc);
    }
    if (e < end) acc = fmaf(hin[(size_t)ss[e] * 64 + lane], swt[e], acc);
    float hh = fmaf(0.9f, acc, 0.1f * x0[(size_t)node * 64 + lane]);
    float d0 = 0.f, d1 = 0.f;
#pragma unroll
    for (int k = 0; k < 64; k += 2) {
      d0 = fmaf(bcast(hh, k), Wreg[k], d0);
      d1 = fmaf(bcast(hh, k + 1), Wreg[k + 1], d1);
    }
    float o = (1.f - beta) * hh + beta * (d0 + d1);
    hout[(size_t)node * 64 + lane] = fmaxf(o, 0.f);
  }
}

// ---------------- out = log_softmax(h @ W_out + b_out) ----------------
__global__ __launch_bounds__(256) void out_k(const float* __restrict__ h, const float* __restrict__ Wout,
                                             const float* __restrict__ bout, float* __restrict__ out, int n) {
  int lane = threadIdx.x & 63;
  int wave = threadIdx.x >> 6;
  float Wreg[64];
#pragma unroll
  for (int k = 0; k < 64; ++k) Wreg[k] = (lane < 40) ? Wout[k * 40 + lane] : 0.f;
  float bb = (lane < 40) ? bout[lane] : 0.f;
  for (int node = blockIdx.x * 4 + wave; node < n; node += gridDim.x * 4) {
    float hv = h[(size_t)node * 64 + lane];
    float d0 = 0.f, d1 = 0.f;
#pragma unroll
    for (int k = 0; k < 64; k += 2) {
      d0 = fmaf(bcast(hv, k), Wreg[k], d0);
      d1 = fmaf(bcast(hv, k + 1), Wreg[k + 1], d1);
    }
    float val = (lane < 40) ? (d0 + d1 + bb) : -INFINITY;
    float m = val;
#pragma unroll
    for (int mask = 32; mask >= 1; mask >>= 1) m = fmaxf(m, __shfl_xor(m, mask, 64));
    float p = (lane < 40) ? expf(val - m) : 0.f;
    float s = p;
#pragma unroll
    for (int mask = 32; mask >= 1; mask >>= 1) s += __shfl_xor(s, mask, 64);
    float ls = val - m - logf(s);
    if (lane < 40) out[(size_t)node * 40 + lane] = ls;
  }
}

extern "C" void kernel_launch(void* const* d_in, const int* in_sizes, int n_in,
                              void* d_out, int out_size, void* d_ws, size_t ws_size,
                              hipStream_t stream) {
  const float* x = (const float*)d_in[0];
  const int* esrc = (const int*)d_in[1];
  const int* edst = (const int*)d_in[2];
  const float* ew = (const float*)d_in[3];
  const float* Win = (const float*)d_in[4];
  const float* bin = (const float*)d_in[5];
  const float* convW = (const float*)d_in[6];
  const float* Wout = (const float*)d_in[7];
  const float* bout = (const float*)d_in[8];
  float* out = (float*)d_out;

  const int N = in_sizes[0] / 128;
  const int E = in_sizes[1];
  const int NC = in_sizes[6] / (64 * 64);

  char* ws = (char*)d_ws;
  size_t off = 0;
  auto alloc = [&](size_t b) {
    void* p = ws + off;
    off += (b + 255) & ~(size_t)255;
    return p;
  };
  float* x0 = (float*)alloc((size_t)N * 64 * 4);
  float* ha = (float*)alloc((size_t)N * 64 * 4);
  float* hb = (float*)alloc((size_t)N * 64 * 4);
  int* deg = (int*)alloc((size_t)N * 4);
  int* rp = (int*)alloc((size_t)(N + 1) * 4);
  int* cur = (int*)alloc((size_t)N * 4);
  int* bsum = (int*)alloc(1024);
  int* ssrc = (int*)alloc((size_t)E * 4);
  float* sw = (float*)alloc((size_t)E * 4);

  hipMemsetAsync(deg, 0, (size_t)N * 4, stream);
  hist_k<<<2048, 256, 0, stream>>>(edst, deg, E);
  int nb = (N + 1023) / 1024;
  scan1_k<<<nb, 1024, 0, stream>>>(deg, rp, bsum, N);
  scan2_k<<<1, 256, 0, stream>>>(bsum, nb);
  scan3_k<<<nb, 1024, 0, stream>>>(rp, cur, bsum, N, E);
  scatter_k<<<2048, 256, 0, stream>>>(esrc, edst, ew, cur, ssrc, sw, E);

  ingemm_k<<<2048, 256, 0, stream>>>(x, Win, bin, x0, N);

  const float* hin = x0;
  float* bufs[2] = {ha, hb};
  for (int l = 0; l < NC; ++l) {
    float beta = logf(0.5f / (float)(l + 1) + 1.0f);
    float* ho = bufs[l & 1];
    layer_k<<<2048, 256, 0, stream>>>(hin, x0, rp, ssrc, sw, convW + (size_t)l * 64 * 64, ho, beta, N);
    hin = ho;
  }
  out_k<<<2048, 256, 0, stream>>>(hin, Wout, bout, out, N);
}

// Round 2
// 986.526 us; speedup vs baseline: 1.3355x; 1.3355x over previous
//
#include <hip/hip_runtime.h>
#include <math.h>

// Wave-uniform broadcast of lane k's value (VALU v_readlane, avoids LDS pipe)
__device__ __forceinline__ float bcast(float v, int k) {
  return __int_as_float(__builtin_amdgcn_readlane(__float_as_int(v), k));
}

// ---------------- CSR build: histogram ----------------
__global__ __launch_bounds__(256) void hist_k(const int* __restrict__ dst, int* __restrict__ deg, int E) {
  for (int e = blockIdx.x * blockDim.x + threadIdx.x; e < E; e += gridDim.x * blockDim.x)
    atomicAdd(&deg[dst[e]], 1);
}

// ---------------- CSR build: 3-kernel exclusive scan ----------------
__global__ __launch_bounds__(1024) void scan1_k(const int* __restrict__ deg, int* __restrict__ rp,
                                                int* __restrict__ bsum, int n) {
  __shared__ int buf[2][1024];
  int tid = threadIdx.x;
  int i = blockIdx.x * 1024 + tid;
  int v = (i < n) ? deg[i] : 0;
  int pp = 0;
  buf[0][tid] = v;
  __syncthreads();
  for (int off = 1; off < 1024; off <<= 1) {
    int t = buf[pp][tid];
    if (tid >= off) t += buf[pp][tid - off];
    buf[pp ^ 1][tid] = t;
    pp ^= 1;
    __syncthreads();
  }
  int inc = buf[pp][tid];
  if (i < n) rp[i] = inc - v;               // exclusive within block
  if (tid == 1023) bsum[blockIdx.x] = inc;  // block total
}

__global__ __launch_bounds__(256) void scan2_k(int* __restrict__ bsum, int nb) {
  __shared__ int buf[2][256];
  int tid = threadIdx.x;
  int v = (tid < nb) ? bsum[tid] : 0;
  int pp = 0;
  buf[0][tid] = v;
  __syncthreads();
  for (int off = 1; off < 256; off <<= 1) {
    int t = buf[pp][tid];
    if (tid >= off) t += buf[pp][tid - off];
    buf[pp ^ 1][tid] = t;
    pp ^= 1;
    __syncthreads();
  }
  if (tid < nb) bsum[tid] = buf[pp][tid] - v;  // exclusive block offsets
}

__global__ __launch_bounds__(1024) void scan3_k(int* __restrict__ rp, int* __restrict__ cur,
                                                const int* __restrict__ bsum, int n, int E) {
  int i = blockIdx.x * 1024 + threadIdx.x;
  if (i < n) {
    int v = rp[i] + bsum[blockIdx.x];
    rp[i] = v;
    cur[i] = v;
  }
  if (i == 0) rp[n] = E;
}

// ---------------- CSR build: counting-sort scatter (packs src+weight) ----------------
__global__ __launch_bounds__(256) void scatter_k(const int* __restrict__ src, const int* __restrict__ dst,
                                                 const float* __restrict__ w, int* __restrict__ cur,
                                                 int2* __restrict__ edge, int E) {
  for (int e = blockIdx.x * blockDim.x + threadIdx.x; e < E; e += gridDim.x * blockDim.x) {
    int d = dst[e];
    int pos = atomicAdd(&cur[d], 1);
    edge[pos] = make_int2(src[e], __float_as_int(w[e]));
  }
}

// ---------------- h = relu(x @ W_in + b_in) ----------------
__global__ __launch_bounds__(256) void ingemm_k(const float* __restrict__ x, const float* __restrict__ Win,
                                                const float* __restrict__ bin, float* __restrict__ x0, int n) {
  int lane = threadIdx.x & 63;
  int wave = threadIdx.x >> 6;
  float Wreg[128];
#pragma unroll
  for (int k = 0; k < 128; ++k) Wreg[k] = Win[k * 64 + lane];
  float bb = bin[lane];
  for (int node = blockIdx.x * 4 + wave; node < n; node += gridDim.x * 4) {
    float xa = x[(size_t)node * 128 + lane];
    float xb = x[(size_t)node * 128 + 64 + lane];
    float a0 = 0.f, a1 = 0.f;
#pragma unroll
    for (int k = 0; k < 64; k += 2) {
      a0 = fmaf(bcast(xa, k), Wreg[k], a0);
      a1 = fmaf(bcast(xa, k + 1), Wreg[k + 1], a1);
    }
#pragma unroll
    for (int k = 0; k < 64; k += 2) {
      a0 = fmaf(bcast(xb, k), Wreg[64 + k], a0);
      a1 = fmaf(bcast(xb, k + 1), Wreg[64 + k + 1], a1);
    }
    float r = a0 + a1 + bb;
    x0[(size_t)node * 64 + lane] = fmaxf(r, 0.f);
  }
}

// ---------------- one GCNII layer ----------------
// SpMM: 4 edges/iter via float4 row-gathers (lane = edge-slot(2b) x feature-quad(4b)),
// unrolled x2 -> 8 edges (2KB) in flight. Then butterfly-reduce edge slots,
// shuffle back to lane=feature, residual mix, register-resident 64x64 dense, relu.
__global__ __launch_bounds__(256) void layer_k(const float4* __restrict__ hin4, const float* __restrict__ x0,
                                               const int* __restrict__ rp, const int2* __restrict__ edge,
                                               const float* __restrict__ W, float* __restrict__ hout,
                                               float beta, int n) {
  int lane = threadIdx.x & 63;
  int wave = threadIdx.x >> 6;
  int q = lane >> 4;    // edge slot 0..3
  int fq = lane & 15;   // feature quad 0..15
  float Wreg[64];
#pragma unroll
  for (int k = 0; k < 64; ++k) Wreg[k] = W[k * 64 + lane];
  for (int node = blockIdx.x * 4 + wave; node < n; node += gridDim.x * 4) {
    int beg = rp[node], end = rp[node + 1];
    float4 acc = make_float4(0.f, 0.f, 0.f, 0.f);
    for (int e0 = beg; e0 < end; e0 += 8) {
      int i0 = e0 + q;
      int i1 = e0 + 4 + q;
      int2 ed0 = (i0 < end) ? edge[i0] : make_int2(0, 0);
      int2 ed1 = (i1 < end) ? edge[i1] : make_int2(0, 0);
      float4 v0 = hin4[(size_t)ed0.x * 16 + fq];
      float4 v1 = hin4[(size_t)ed1.x * 16 + fq];
      float w0 = __int_as_float(ed0.y);
      float w1 = __int_as_float(ed1.y);
      acc.x = fmaf(v0.x, w0, acc.x);
      acc.y = fmaf(v0.y, w0, acc.y);
      acc.z = fmaf(v0.z, w0, acc.z);
      acc.w = fmaf(v0.w, w0, acc.w);
      acc.x = fmaf(v1.x, w1, acc.x);
      acc.y = fmaf(v1.y, w1, acc.y);
      acc.z = fmaf(v1.z, w1, acc.z);
      acc.w = fmaf(v1.w, w1, acc.w);
    }
    // sum the 4 edge slots (all lanes end with the full quad sums)
#pragma unroll
    for (int m = 16; m <= 32; m <<= 1) {
      acc.x += __shfl_xor(acc.x, m, 64);
      acc.y += __shfl_xor(acc.y, m, 64);
      acc.z += __shfl_xor(acc.z, m, 64);
      acc.w += __shfl_xor(acc.w, m, 64);
    }
    // redistribute to lane = feature: feature l lives at lane l>>2, element l&3
    int srcl = lane >> 2;
    float r0 = __shfl(acc.x, srcl, 64);
    float r1 = __shfl(acc.y, srcl, 64);
    float r2 = __shfl(acc.z, srcl, 64);
    float r3 = __shfl(acc.w, srcl, 64);
    int j = lane & 3;
    float aggv = (j == 0) ? r0 : (j == 1) ? r1 : (j == 2) ? r2 : r3;
    float hh = fmaf(0.9f, aggv, 0.1f * x0[(size_t)node * 64 + lane]);
    float d0 = 0.f, d1 = 0.f;
#pragma unroll
    for (int k = 0; k < 64; k += 2) {
      d0 = fmaf(bcast(hh, k), Wreg[k], d0);
      d1 = fmaf(bcast(hh, k + 1), Wreg[k + 1], d1);
    }
    float o = (1.f - beta) * hh + beta * (d0 + d1);
    hout[(size_t)node * 64 + lane] = fmaxf(o, 0.f);
  }
}

// ---------------- out = log_softmax(h @ W_out + b_out) ----------------
__global__ __launch_bounds__(256) void out_k(const float* __restrict__ h, const float* __restrict__ Wout,
                                             const float* __restrict__ bout, float* __restrict__ out, int n) {
  int lane = threadIdx.x & 63;
  int wave = threadIdx.x >> 6;
  float Wreg[64];
#pragma unroll
  for (int k = 0; k < 64; ++k) Wreg[k] = (lane < 40) ? Wout[k * 40 + lane] : 0.f;
  float bb = (lane < 40) ? bout[lane] : 0.f;
  for (int node = blockIdx.x * 4 + wave; node < n; node += gridDim.x * 4) {
    float hv = h[(size_t)node * 64 + lane];
    float d0 = 0.f, d1 = 0.f;
#pragma unroll
    for (int k = 0; k < 64; k += 2) {
      d0 = fmaf(bcast(hv, k), Wreg[k], d0);
      d1 = fmaf(bcast(hv, k + 1), Wreg[k + 1], d1);
    }
    float val = (lane < 40) ? (d0 + d1 + bb) : -INFINITY;
    float m = val;
#pragma unroll
    for (int mask = 32; mask >= 1; mask >>= 1) m = fmaxf(m, __shfl_xor(m, mask, 64));
    float p = (lane < 40) ? expf(val - m) : 0.f;
    float s = p;
#pragma unroll
    for (int mask = 32; mask >= 1; mask >>= 1) s += __shfl_xor(s, mask, 64);
    float ls = val - m - logf(s);
    if (lane < 40) out[(size_t)node * 40 + lane] = ls;
  }
}

extern "C" void kernel_launch(void* const* d_in, const int* in_sizes, int n_in,
                              void* d_out, int out_size, void* d_ws, size_t ws_size,
                              hipStream_t stream) {
  const float* x = (const float*)d_in[0];
  const int* esrc = (const int*)d_in[1];
  const int* edst = (const int*)d_in[2];
  const float* ew = (const float*)d_in[3];
  const float* Win = (const float*)d_in[4];
  const float* bin = (const float*)d_in[5];
  const float* convW = (const float*)d_in[6];
  const float* Wout = (const float*)d_in[7];
  const float* bout = (const float*)d_in[8];
  float* out = (float*)d_out;

  const int N = in_sizes[0] / 128;
  const int E = in_sizes[1];
  const int NC = in_sizes[6] / (64 * 64);

  char* ws = (char*)d_ws;
  size_t off = 0;
  auto alloc = [&](size_t b) {
    void* p = ws + off;
    off += (b + 255) & ~(size_t)255;
    return p;
  };
  float* x0 = (float*)alloc((size_t)N * 64 * 4);
  float* ha = (float*)alloc((size_t)N * 64 * 4);
  float* hb = (float*)alloc((size_t)N * 64 * 4);
  int* deg = (int*)alloc((size_t)N * 4);
  int* rp = (int*)alloc((size_t)(N + 1) * 4);
  int* cur = (int*)alloc((size_t)N * 4);
  int* bsum = (int*)alloc(1024);
  int2* edge = (int2*)alloc((size_t)E * 8);

  hipMemsetAsync(deg, 0, (size_t)N * 4, stream);
  hist_k<<<2048, 256, 0, stream>>>(edst, deg, E);
  int nb = (N + 1023) / 1024;
  scan1_k<<<nb, 1024, 0, stream>>>(deg, rp, bsum, N);
  scan2_k<<<1, 256, 0, stream>>>(bsum, nb);
  scan3_k<<<nb, 1024, 0, stream>>>(rp, cur, bsum, N, E);
  scatter_k<<<2048, 256, 0, stream>>>(esrc, edst, ew, cur, edge, E);

  ingemm_k<<<2048, 256, 0, stream>>>(x, Win, bin, x0, N);

  const float* hin = x0;
  float* bufs[2] = {ha, hb};
  for (int l = 0; l < NC; ++l) {
    float beta = logf(0.5f / (float)(l + 1) + 1.0f);
    float* ho = bufs[l & 1];
    layer_k<<<2048, 256, 0, stream>>>((const float4*)hin, x0, rp, edge, convW + (size_t)l * 64 * 64, ho, beta, N);
    hin = ho;
  }
  out_k<<<2048, 256, 0, stream>>>(hin, Wout, bout, out, N);
}